// Round 1
// baseline (474.674 us; speedup 1.0000x reference)
//
#include <hip/hip_runtime.h>
#include <stdint.h>

#pragma clang fp contract(off)

typedef unsigned int u32;
typedef unsigned long long u64;

#define HH 2048
#define WW 2048
#define HW (HH * WW)
#define TOPK 1000
#define CAP 4096

// ---- workspace layout (bytes) ----
#define OFF_CLOC   0u
#define OFF_HIST1  16777216u                  // 4096 * 4
#define OFF_HIST2  (OFF_HIST1 + 16384u)       // 65536 * 4
#define OFF_META   (OFF_HIST2 + 262144u)      // 64 * 4
#define OFF_CAND   (OFF_META + 256u)          // CAP * 8
#define OFF_TIDX   (OFF_CAND + CAP * 8u)      // 1000 * 4 (padded)
#define OFF_TSCR   (OFF_TIDX + 4096u)
#define OFF_LINES  (OFF_TSCR + 4096u)         // 4000 * 4 (padded)
#define OFF_ADJ    (OFF_LINES + 16384u)       // 1000 * 16 * 8 = 128000
#define OFF_DROP   (OFF_ADJ + 128000u)        // 16 * 8
// total ~17.26 MB

// meta indices
#define M_B1    0
#define M_C1    1
#define M_T28   2
#define M_NCAND 3
#define M_CNT   4

__device__ __forceinline__ float softmax2(float h0, float h1) {
    // mirrors jax.nn.softmax over 2 channels, take channel 1
    float m  = fmaxf(h0, h1);
    float e0 = expf(h0 - m);
    float e1 = expf(h1 - m);
    return e1 / (e0 + e1);
}

__device__ __forceinline__ float sigm(float x) {
    return 1.0f / (1.0f + expf(-x));
}

// jloc key for pixel i: peak-NMS damped softmax prob, as monotone uint bits
__device__ __forceinline__ u32 jkey(const float* __restrict__ cloc, int i) {
    int y = i >> 11, x = i & 2047;
    float c = cloc[i];
    float m = c;
    #pragma unroll
    for (int dy = -1; dy <= 1; dy++) {
        int yy = y + dy;
        if ((unsigned)yy > 2047u) continue;
        #pragma unroll
        for (int dx = -1; dx <= 1; dx++) {
            int xx = x + dx;
            if ((unsigned)xx > 2047u) continue;
            m = fmaxf(m, cloc[(yy << 11) + xx]);
        }
    }
    float v = c * ((c == m) ? 1.0f : 0.8f);
    return __float_as_uint(v);   // v > 0 always -> bit order == value order
}

// ---- K1: softmax channel-1 prob ----
__global__ void k_cloc(const float* __restrict__ hm, float* __restrict__ cloc) {
    int i = blockIdx.x * blockDim.x + threadIdx.x;   // HW/4 threads
    const float4* a4 = (const float4*)hm;
    const float4* b4 = (const float4*)(hm + HW);
    float4 a = a4[i], b = b4[i];
    float4 c;
    c.x = softmax2(a.x, b.x);
    c.y = softmax2(a.y, b.y);
    c.z = softmax2(a.z, b.z);
    c.w = softmax2(a.w, b.w);
    ((float4*)cloc)[i] = c;
}

// ---- K2: stage-1 histogram over top 12 bits ----
__global__ void k_hist1(const float* __restrict__ cloc, u32* __restrict__ hist1) {
    __shared__ u32 lh[4096];
    for (int b = threadIdx.x; b < 4096; b += blockDim.x) lh[b] = 0;
    __syncthreads();
    int stride = gridDim.x * blockDim.x;
    for (int i = blockIdx.x * blockDim.x + threadIdx.x; i < HW; i += stride) {
        u32 key = jkey(cloc, i);
        atomicAdd(&lh[key >> 20], 1u);
    }
    __syncthreads();
    for (int b = threadIdx.x; b < 4096; b += blockDim.x) {
        u32 v = lh[b];
        if (v) atomicAdd(&hist1[b], v);
    }
}

// ---- K3: scan stage-1 hist from top, find bucket b1 + count above ----
__global__ void k_scan1(const u32* __restrict__ hist1, u32* __restrict__ meta) {
    __shared__ u32 csum[1024];
    int t = threadIdx.x;
    u32 h[4]; u32 c = 0;
    #pragma unroll
    for (int b = 0; b < 4; b++) { h[b] = hist1[t * 4 + b]; c += h[b]; }
    csum[t] = c;
    __syncthreads();
    for (int off = 1; off < 1024; off <<= 1) {
        u32 v = (t + off < 1024) ? csum[t + off] : 0;
        __syncthreads();
        csum[t] += v;
        __syncthreads();
    }
    u32 run = csum[t] - c;              // count in buckets above this chunk
    for (int b = 3; b >= 0; b--) {
        u32 cnt = h[b];
        if (run < TOPK && run + cnt >= TOPK) {
            meta[M_B1] = (u32)(t * 4 + b);
            meta[M_C1] = run;
        }
        run += cnt;
    }
}

// ---- K4: stage-2 histogram (next 16 bits) restricted to bucket b1 ----
__global__ void k_hist2(const float* __restrict__ cloc, const u32* __restrict__ meta,
                        u32* __restrict__ hist2) {
    u32 b1 = meta[M_B1];
    int stride = gridDim.x * blockDim.x;
    for (int i = blockIdx.x * blockDim.x + threadIdx.x; i < HW; i += stride) {
        u32 key = jkey(cloc, i);
        if ((key >> 20) == b1) atomicAdd(&hist2[(key >> 4) & 0xFFFFu], 1u);
    }
}

// ---- K5: scan stage-2 hist, produce 28-bit floor threshold ----
__global__ void k_scan2(const u32* __restrict__ hist2, u32* __restrict__ meta) {
    __shared__ u32 csum[1024];
    int t = threadIdx.x;
    u32 C1 = meta[M_C1];
    u32 c = 0;
    for (int b = 0; b < 64; b++) c += hist2[t * 64 + b];
    csum[t] = c;
    __syncthreads();
    for (int off = 1; off < 1024; off <<= 1) {
        u32 v = (t + off < 1024) ? csum[t + off] : 0;
        __syncthreads();
        csum[t] += v;
        __syncthreads();
    }
    u32 run = C1 + (csum[t] - c);
    for (int b = 63; b >= 0; b--) {
        u32 cnt = hist2[t * 64 + b];
        if (run < TOPK && run + cnt >= TOPK) {
            meta[M_T28]   = (meta[M_B1] << 16) | (u32)(t * 64 + b);
            meta[M_NCAND] = run + cnt;
        }
        run += cnt;
    }
}

// ---- K6: collect candidates >= threshold floor ----
__global__ void k_collect(const float* __restrict__ cloc, u32* __restrict__ meta,
                          u64* __restrict__ cand) {
    u32 T28 = meta[M_T28];
    int stride = gridDim.x * blockDim.x;
    for (int i = blockIdx.x * blockDim.x + threadIdx.x; i < HW; i += stride) {
        u32 key = jkey(cloc, i);
        if ((key >> 4) >= T28) {
            u32 pos = atomicAdd(&meta[M_CNT], 1u);
            if (pos < CAP)
                cand[pos] = ((u64)key << 32) | (u64)(0xFFFFFFFFu - (u32)i);
        }
    }
}

// ---- K7: bitonic sort candidates, emit exact top-1000 (value desc, idx asc) ----
__global__ void k_sort(const u64* __restrict__ cand, const u32* __restrict__ meta,
                       u32* __restrict__ tidx, float* __restrict__ tscr) {
    __shared__ u64 s[CAP];
    int t = threadIdx.x;     // 1024
    u32 n = meta[M_CNT];
    if (n > CAP) n = CAP;
    for (int i = t; i < CAP; i += 1024) s[i] = (i < (int)n) ? cand[i] : 0ull;
    __syncthreads();
    for (int k = 2; k <= CAP; k <<= 1) {
        for (int j = k >> 1; j > 0; j >>= 1) {
            for (int i = t; i < CAP; i += 1024) {
                int ij = i ^ j;
                if (ij > i) {
                    u64 a = s[i], b = s[ij];
                    bool up = ((i & k) == 0);
                    bool sw = up ? (a > b) : (a < b);
                    if (sw) { s[i] = b; s[ij] = a; }
                }
            }
            __syncthreads();
        }
    }
    // ascending in s; rank r best = s[CAP-1-r]
    for (int r = t; r < TOPK; r += 1024) {
        u64 e = s[CAP - 1 - r];
        tidx[r] = 0xFFFFFFFFu - (u32)(e & 0xFFFFFFFFull);
        tscr[r] = __uint_as_float((u32)(e >> 32));
    }
}

// ---- K8: per-junction line geometry ----
__global__ void k_lines(const float* __restrict__ hm, const u32* __restrict__ tidx,
                        float* __restrict__ lines) {
    int k = blockIdx.x * blockDim.x + threadIdx.x;
    if (k >= TOPK) return;
    int idx = (int)tidx[k];
    int row = idx >> 11, col = idx & 2047;
    float joff1 = sigm(hm[2 * HW + idx]);   // y offset
    float joff0 = sigm(hm[3 * HW + idx]);   // x offset
    float y = (float)row + joff1;
    float x = (float)col + joff0;
    float r = sigm(hm[4 * HW + idx]) * 64.0f;
    float a = sigm(hm[5 * HW + idx]) * 3.14159265358979323846f;
    float dx = cosf(a) * r;
    float dy = -fabsf(sinf(a)) * r;
    lines[4 * k + 0] = x + dx;
    lines[4 * k + 1] = y + dy;
    lines[4 * k + 2] = x - dx;
    lines[4 * k + 3] = y - dy;
}

// ---- K9: adjacency bit-matrix (d <= 2, no diagonal) ----
__global__ void k_adj(const float* __restrict__ lines, u64* __restrict__ adj) {
    int i = blockIdx.x;          // 1000 rows
    int lane = threadIdx.x;      // 64
    float ax0 = lines[4 * i + 0], ay0 = lines[4 * i + 1];
    float ax1 = lines[4 * i + 2], ay1 = lines[4 * i + 3];
    for (int w = 0; w < 16; w++) {
        int j = w * 64 + lane;
        bool pred = false;
        if (j < TOPK && j != i) {
            float bx0 = lines[4 * j + 0], by0 = lines[4 * j + 1];
            float bx1 = lines[4 * j + 2], by1 = lines[4 * j + 3];
            float t0, t1;
            t0 = ax0 - bx0; t1 = ay0 - by0; float e00 = t0 * t0 + t1 * t1;
            t0 = ax1 - bx1; t1 = ay1 - by1; float e11 = t0 * t0 + t1 * t1;
            t0 = ax1 - bx0; t1 = ay1 - by0; float e10 = t0 * t0 + t1 * t1;
            t0 = ax0 - bx1; t1 = ay0 - by1; float e01 = t0 * t0 + t1 * t1;
            float d = fminf(e00 + e11, e10 + e01);
            pred = (d <= 2.0f);
        }
        u64 b = __ballot(pred);
        if (lane == 0) adj[i * 16 + w] = b;
    }
}

// ---- K10: sequential greedy suppression (single wave) ----
__global__ void __launch_bounds__(64) k_greedy(const u64* __restrict__ adjG,
                                               u64* __restrict__ dropG) {
    extern __shared__ u64 adjL[];          // 16000 u64 = 125 KB
    int lane = threadIdx.x;
    for (int t = lane; t < TOPK * 16; t += 64) adjL[t] = adjG[t];
    __syncthreads();
    int w = lane & 15;                     // word owned (replicated x4)
    u64 dropW = adjL[w];                   // drop init = adj row 0
    for (int i = 1; i <= 997; i++) {       // fori_loop(1, K-2)
        u64 bi = __shfl(dropW, i >> 6);    // word containing bit i
        if (((bi >> (i & 63)) & 1ull) == 0ull) {
            u64 row = adjL[i * 16 + w];
            int iw = i >> 6, ib = i & 63;
            u64 mask = (w < iw) ? 0ull
                     : (w > iw) ? ~0ull
                     : ((ib == 63) ? 0ull : (~0ull << (ib + 1)));
            dropW |= row & mask;
        }
    }
    if (lane < 16) dropG[lane] = dropW;
}

// ---- K11: apply keep mask, write outputs ----
__global__ void k_final(const float* __restrict__ lines, const float* __restrict__ tscr,
                        const u64* __restrict__ dropG, float* __restrict__ out) {
    int k = blockIdx.x * blockDim.x + threadIdx.x;
    if (k >= TOPK) return;
    u64 dw = dropG[k >> 6];
    float f = ((dw >> (k & 63)) & 1ull) ? 0.0f : 1.0f;
    out[4 * k + 0] = lines[4 * k + 0] * f;
    out[4 * k + 1] = lines[4 * k + 1] * f;
    out[4 * k + 2] = lines[4 * k + 2] * f;
    out[4 * k + 3] = lines[4 * k + 3] * f;
    out[4000 + k]  = tscr[k] * f;
}

extern "C" void kernel_launch(void* const* d_in, const int* in_sizes, int n_in,
                              void* d_out, int out_size, void* d_ws, size_t ws_size,
                              hipStream_t stream) {
    const float* hm = (const float*)d_in[0];
    char* ws = (char*)d_ws;

    float* cloc  = (float*)(ws + OFF_CLOC);
    u32*   hist1 = (u32*)  (ws + OFF_HIST1);
    u32*   hist2 = (u32*)  (ws + OFF_HIST2);
    u32*   meta  = (u32*)  (ws + OFF_META);
    u64*   cand  = (u64*)  (ws + OFF_CAND);
    u32*   tidx  = (u32*)  (ws + OFF_TIDX);
    float* tscr  = (float*)(ws + OFF_TSCR);
    float* lines = (float*)(ws + OFF_LINES);
    u64*   adj   = (u64*)  (ws + OFF_ADJ);
    u64*   drop  = (u64*)  (ws + OFF_DROP);

    // zero hist1 + hist2 + meta (contiguous)
    hipMemsetAsync(ws + OFF_HIST1, 0, 16384u + 262144u + 256u, stream);

    k_cloc   <<<HW / 4 / 256, 256, 0, stream>>>(hm, cloc);
    k_hist1  <<<512, 256, 0, stream>>>(cloc, hist1);
    k_scan1  <<<1, 1024, 0, stream>>>(hist1, meta);
    k_hist2  <<<512, 256, 0, stream>>>(cloc, meta, hist2);
    k_scan2  <<<1, 1024, 0, stream>>>(hist2, meta);
    k_collect<<<512, 256, 0, stream>>>(cloc, meta, cand);
    k_sort   <<<1, 1024, 0, stream>>>(cand, meta, tidx, tscr);
    k_lines  <<<4, 256, 0, stream>>>(hm, tidx, lines);
    k_adj    <<<TOPK, 64, 0, stream>>>(lines, adj);

    hipFuncSetAttribute((const void*)k_greedy,
                        hipFuncAttributeMaxDynamicSharedMemorySize, TOPK * 16 * 8);
    k_greedy <<<1, 64, TOPK * 16 * 8, stream>>>(adj, drop);

    k_final  <<<4, 256, 0, stream>>>(lines, tscr, drop, (float*)d_out);
}

// Round 2
// 221.834 us; speedup vs baseline: 2.1398x; 2.1398x over previous
//
#include <hip/hip_runtime.h>
#include <stdint.h>

#pragma clang fp contract(off)

typedef unsigned int u32;
typedef unsigned long long u64;

#define HH 2048
#define WW 2048
#define HW (HH * WW)
#define TOPK 1000
#define CAP 4096

// ---- workspace layout (bytes) ----
#define OFF_CLOC   0u
#define OFF_HIST1  16777216u                   // 4096 * 4
#define OFF_HIST2  (OFF_HIST1 + 16384u)        // 65536 * 4
#define OFF_META   (OFF_HIST2 + 262144u)       // 64 * 4
#define OFF_NZ     (OFF_META + 256u)           // 16 * 8 (nonzero-row bitmask)
#define OFF_CAND   (OFF_NZ + 256u)             // CAP * 8
#define OFF_TIDX   (OFF_CAND + CAP * 8u)       // 1000 * 4 (padded)
#define OFF_TSCR   (OFF_TIDX + 4096u)
#define OFF_LINES  (OFF_TSCR + 4096u)          // 4000 * 4 (padded)
#define OFF_ADJ    (OFF_LINES + 16384u)        // 1000 * 16 * 8 = 128000 (pad 131072)
#define OFF_DROP   (OFF_ADJ + 131072u)         // 16 * 8 (pad 256)
#define OFF_KEYS   (OFF_DROP + 256u)           // HW * 4 (optional cache)
#define WS_NEED_KEYS (OFF_KEYS + (u64)HW * 4u)

// meta indices
#define M_B1    0
#define M_C1    1
#define M_T28   2
#define M_NCAND 3
#define M_CNT   4

__device__ __forceinline__ float softmax2(float h0, float h1) {
    float m  = fmaxf(h0, h1);
    float e0 = expf(h0 - m);
    float e1 = expf(h1 - m);
    return e1 / (e0 + e1);
}

__device__ __forceinline__ float sigm(float x) {
    return 1.0f / (1.0f + expf(-x));
}

// jloc key for pixel i: peak-NMS damped softmax prob, as monotone uint bits
__device__ __forceinline__ u32 jkey(const float* __restrict__ cloc, int i) {
    int y = i >> 11, x = i & 2047;
    float c = cloc[i];
    float m = c;
    #pragma unroll
    for (int dy = -1; dy <= 1; dy++) {
        int yy = y + dy;
        if ((unsigned)yy > 2047u) continue;
        #pragma unroll
        for (int dx = -1; dx <= 1; dx++) {
            int xx = x + dx;
            if ((unsigned)xx > 2047u) continue;
            m = fmaxf(m, cloc[(yy << 11) + xx]);
        }
    }
    float v = c * ((c == m) ? 1.0f : 0.8f);
    return __float_as_uint(v);   // v > 0 always -> bit order == value order
}

// ---- K1: softmax channel-1 prob ----
__global__ void k_cloc(const float* __restrict__ hm, float* __restrict__ cloc) {
    int i = blockIdx.x * blockDim.x + threadIdx.x;   // HW/4 threads
    const float4* a4 = (const float4*)hm;
    const float4* b4 = (const float4*)(hm + HW);
    float4 a = a4[i], b = b4[i];
    float4 c;
    c.x = softmax2(a.x, b.x);
    c.y = softmax2(a.y, b.y);
    c.z = softmax2(a.z, b.z);
    c.w = softmax2(a.w, b.w);
    ((float4*)cloc)[i] = c;
}

// ---- K2: stage-1 histogram over top 12 bits (optionally caching keys) ----
__global__ void k_hist1(const float* __restrict__ cloc, u32* __restrict__ hist1,
                        u32* __restrict__ keys) {
    __shared__ u32 lh[4096];
    for (int b = threadIdx.x; b < 4096; b += blockDim.x) lh[b] = 0;
    __syncthreads();
    int stride = gridDim.x * blockDim.x;
    for (int i = blockIdx.x * blockDim.x + threadIdx.x; i < HW; i += stride) {
        u32 key = jkey(cloc, i);
        if (keys) keys[i] = key;
        atomicAdd(&lh[key >> 20], 1u);
    }
    __syncthreads();
    for (int b = threadIdx.x; b < 4096; b += blockDim.x) {
        u32 v = lh[b];
        if (v) atomicAdd(&hist1[b], v);
    }
}

// ---- K3: scan stage-1 hist from top, find bucket b1 + count above ----
__global__ void k_scan1(const u32* __restrict__ hist1, u32* __restrict__ meta) {
    __shared__ u32 csum[1024];
    int t = threadIdx.x;
    u32 h[4]; u32 c = 0;
    #pragma unroll
    for (int b = 0; b < 4; b++) { h[b] = hist1[t * 4 + b]; c += h[b]; }
    csum[t] = c;
    __syncthreads();
    for (int off = 1; off < 1024; off <<= 1) {
        u32 v = (t + off < 1024) ? csum[t + off] : 0;
        __syncthreads();
        csum[t] += v;
        __syncthreads();
    }
    u32 run = csum[t] - c;              // count in buckets above this chunk
    for (int b = 3; b >= 0; b--) {
        u32 cnt = h[b];
        if (run < TOPK && run + cnt >= TOPK) {
            meta[M_B1] = (u32)(t * 4 + b);
            meta[M_C1] = run;
        }
        run += cnt;
    }
}

// ---- K4: stage-2 histogram (next 16 bits) restricted to bucket b1 ----
__global__ void k_hist2(const float* __restrict__ cloc, const u32* __restrict__ keys,
                        const u32* __restrict__ meta, u32* __restrict__ hist2) {
    u32 b1 = meta[M_B1];
    int stride = gridDim.x * blockDim.x;
    for (int i = blockIdx.x * blockDim.x + threadIdx.x; i < HW; i += stride) {
        u32 key = keys ? keys[i] : jkey(cloc, i);
        if ((key >> 20) == b1) atomicAdd(&hist2[(key >> 4) & 0xFFFFu], 1u);
    }
}

// ---- K5: scan stage-2 hist, produce 28-bit floor threshold ----
__global__ void k_scan2(const u32* __restrict__ hist2, u32* __restrict__ meta) {
    __shared__ u32 csum[1024];
    int t = threadIdx.x;
    u32 C1 = meta[M_C1];
    u32 c = 0;
    for (int b = 0; b < 64; b++) c += hist2[t * 64 + b];
    csum[t] = c;
    __syncthreads();
    for (int off = 1; off < 1024; off <<= 1) {
        u32 v = (t + off < 1024) ? csum[t + off] : 0;
        __syncthreads();
        csum[t] += v;
        __syncthreads();
    }
    u32 run = C1 + (csum[t] - c);
    for (int b = 63; b >= 0; b--) {
        u32 cnt = hist2[t * 64 + b];
        if (run < TOPK && run + cnt >= TOPK) {
            meta[M_T28]   = (meta[M_B1] << 16) | (u32)(t * 64 + b);
            meta[M_NCAND] = run + cnt;
        }
        run += cnt;
    }
}

// ---- K6: collect candidates >= threshold floor ----
__global__ void k_collect(const float* __restrict__ cloc, const u32* __restrict__ keys,
                          u32* __restrict__ meta, u64* __restrict__ cand) {
    u32 T28 = meta[M_T28];
    int stride = gridDim.x * blockDim.x;
    for (int i = blockIdx.x * blockDim.x + threadIdx.x; i < HW; i += stride) {
        u32 key = keys ? keys[i] : jkey(cloc, i);
        if ((key >> 4) >= T28) {
            u32 pos = atomicAdd(&meta[M_CNT], 1u);
            if (pos < CAP)
                cand[pos] = ((u64)key << 32) | (u64)(0xFFFFFFFFu - (u32)i);
        }
    }
}

// ---- K7: bitonic sort candidates, emit exact top-1000 (value desc, idx asc) ----
__global__ void k_sort(const u64* __restrict__ cand, const u32* __restrict__ meta,
                       u32* __restrict__ tidx, float* __restrict__ tscr) {
    __shared__ u64 s[CAP];
    int t = threadIdx.x;     // 1024
    u32 n = meta[M_CNT];
    if (n > CAP) n = CAP;
    for (int i = t; i < CAP; i += 1024) s[i] = (i < (int)n) ? cand[i] : 0ull;
    __syncthreads();
    for (int k = 2; k <= CAP; k <<= 1) {
        for (int j = k >> 1; j > 0; j >>= 1) {
            for (int i = t; i < CAP; i += 1024) {
                int ij = i ^ j;
                if (ij > i) {
                    u64 a = s[i], b = s[ij];
                    bool up = ((i & k) == 0);
                    bool sw = up ? (a > b) : (a < b);
                    if (sw) { s[i] = b; s[ij] = a; }
                }
            }
            __syncthreads();
        }
    }
    // ascending in s; rank r best = s[CAP-1-r]
    for (int r = t; r < TOPK; r += 1024) {
        u64 e = s[CAP - 1 - r];
        tidx[r] = 0xFFFFFFFFu - (u32)(e & 0xFFFFFFFFull);
        tscr[r] = __uint_as_float((u32)(e >> 32));
    }
}

// ---- K8: per-junction line geometry ----
__global__ void k_lines(const float* __restrict__ hm, const u32* __restrict__ tidx,
                        float* __restrict__ lines) {
    int k = blockIdx.x * blockDim.x + threadIdx.x;
    if (k >= TOPK) return;
    int idx = (int)tidx[k];
    int row = idx >> 11, col = idx & 2047;
    float joff1 = sigm(hm[2 * HW + idx]);   // y offset
    float joff0 = sigm(hm[3 * HW + idx]);   // x offset
    float y = (float)row + joff1;
    float x = (float)col + joff0;
    float r = sigm(hm[4 * HW + idx]) * 64.0f;
    float a = sigm(hm[5 * HW + idx]) * 3.14159265358979323846f;
    float dx = cosf(a) * r;
    float dy = -fabsf(sinf(a)) * r;
    lines[4 * k + 0] = x + dx;
    lines[4 * k + 1] = y + dy;
    lines[4 * k + 2] = x - dx;
    lines[4 * k + 3] = y - dy;
}

// ---- K9: adjacency bit-matrix (d <= 2, no diagonal) + nonzero-row mask ----
// nz bit i set iff i in [1,997] and row i has any neighbor j > i
// (rows failing this are provably no-ops in the greedy loop: cand == drop).
__global__ void k_adj(const float* __restrict__ lines, u64* __restrict__ adj,
                      u64* __restrict__ nz) {
    int i = blockIdx.x;          // 1000 rows
    int lane = threadIdx.x;      // 64
    float ax0 = lines[4 * i + 0], ay0 = lines[4 * i + 1];
    float ax1 = lines[4 * i + 2], ay1 = lines[4 * i + 3];
    int iw = i >> 6, ib = i & 63;
    bool any = false;
    for (int w = 0; w < 16; w++) {
        int j = w * 64 + lane;
        bool pred = false;
        if (j < TOPK && j != i) {
            float bx0 = lines[4 * j + 0], by0 = lines[4 * j + 1];
            float bx1 = lines[4 * j + 2], by1 = lines[4 * j + 3];
            float t0, t1;
            t0 = ax0 - bx0; t1 = ay0 - by0; float e00 = t0 * t0 + t1 * t1;
            t0 = ax1 - bx1; t1 = ay1 - by1; float e11 = t0 * t0 + t1 * t1;
            t0 = ax1 - bx0; t1 = ay1 - by0; float e10 = t0 * t0 + t1 * t1;
            t0 = ax0 - bx1; t1 = ay0 - by1; float e01 = t0 * t0 + t1 * t1;
            float d = fminf(e00 + e11, e10 + e01);
            pred = (d <= 2.0f);
        }
        u64 b = __ballot(pred);
        if (lane == 0) {
            adj[i * 16 + w] = b;
            u64 mask = (w < iw) ? 0ull
                     : (w > iw) ? ~0ull
                     : ((ib == 63) ? 0ull : (~0ull << (ib + 1)));
            if ((b & mask) != 0ull) any = true;
        }
    }
    if (lane == 0 && any && i >= 1 && i <= TOPK - 3) {
        atomicOr(&nz[iw], 1ull << ib);
    }
}

// ---- K10: sequential greedy suppression, visiting only nonzero rows ----
__global__ void __launch_bounds__(64) k_greedy(const u64* __restrict__ adjG,
                                               const u64* __restrict__ nzG,
                                               u64* __restrict__ dropG) {
    int lane = threadIdx.x;
    int w = lane & 15;                       // drop word owned (replicated x4)
    u64 nzmy = (lane < 16) ? nzG[lane] : 0ull;
    u64 dropW = adjG[w];                     // drop init = adj row 0
    for (int wi = 0; wi < 16; wi++) {
        u64 bits = __shfl(nzmy, wi);         // wave-uniform
        while (bits) {
            int b = __builtin_ctzll(bits);
            bits &= bits - 1;
            int i = wi * 64 + b;
            u64 di = __shfl(dropW, wi);      // word containing bit i
            if (((di >> b) & 1ull) == 0ull) {
                u64 row = adjG[i * 16 + w];
                u64 mask = (w < wi) ? 0ull
                         : (w > wi) ? ~0ull
                         : ((b == 63) ? 0ull : (~0ull << (b + 1)));
                dropW |= row & mask;
            }
        }
    }
    if (lane < 16) dropG[lane] = dropW;
}

// ---- K11: apply keep mask, write outputs ----
__global__ void k_final(const float* __restrict__ lines, const float* __restrict__ tscr,
                        const u64* __restrict__ dropG, float* __restrict__ out) {
    int k = blockIdx.x * blockDim.x + threadIdx.x;
    if (k >= TOPK) return;
    u64 dw = dropG[k >> 6];
    float f = ((dw >> (k & 63)) & 1ull) ? 0.0f : 1.0f;
    out[4 * k + 0] = lines[4 * k + 0] * f;
    out[4 * k + 1] = lines[4 * k + 1] * f;
    out[4 * k + 2] = lines[4 * k + 2] * f;
    out[4 * k + 3] = lines[4 * k + 3] * f;
    out[4000 + k]  = tscr[k] * f;
}

extern "C" void kernel_launch(void* const* d_in, const int* in_sizes, int n_in,
                              void* d_out, int out_size, void* d_ws, size_t ws_size,
                              hipStream_t stream) {
    const float* hm = (const float*)d_in[0];
    char* ws = (char*)d_ws;

    float* cloc  = (float*)(ws + OFF_CLOC);
    u32*   hist1 = (u32*)  (ws + OFF_HIST1);
    u32*   hist2 = (u32*)  (ws + OFF_HIST2);
    u32*   meta  = (u32*)  (ws + OFF_META);
    u64*   nz    = (u64*)  (ws + OFF_NZ);
    u64*   cand  = (u64*)  (ws + OFF_CAND);
    u32*   tidx  = (u32*)  (ws + OFF_TIDX);
    float* tscr  = (float*)(ws + OFF_TSCR);
    float* lines = (float*)(ws + OFF_LINES);
    u64*   adj   = (u64*)  (ws + OFF_ADJ);
    u64*   drop  = (u64*)  (ws + OFF_DROP);
    u32*   keys  = (ws_size >= WS_NEED_KEYS) ? (u32*)(ws + OFF_KEYS) : (u32*)0;

    // zero hist1 + hist2 + meta + nz (contiguous)
    hipMemsetAsync(ws + OFF_HIST1, 0, 16384u + 262144u + 256u + 256u, stream);

    k_cloc   <<<HW / 4 / 256, 256, 0, stream>>>(hm, cloc);
    k_hist1  <<<512, 256, 0, stream>>>(cloc, hist1, keys);
    k_scan1  <<<1, 1024, 0, stream>>>(hist1, meta);
    k_hist2  <<<512, 256, 0, stream>>>(cloc, keys, meta, hist2);
    k_scan2  <<<1, 1024, 0, stream>>>(hist2, meta);
    k_collect<<<512, 256, 0, stream>>>(cloc, keys, meta, cand);
    k_sort   <<<1, 1024, 0, stream>>>(cand, meta, tidx, tscr);
    k_lines  <<<4, 256, 0, stream>>>(hm, tidx, lines);
    k_adj    <<<TOPK, 64, 0, stream>>>(lines, adj, nz);
    k_greedy <<<1, 64, 0, stream>>>(adj, nz, drop);
    k_final  <<<4, 256, 0, stream>>>(lines, tscr, drop, (float*)d_out);
}